// Round 17
// baseline (120.307 us; speedup 1.0000x reference)
//
#include <hip/hip_runtime.h>

#define S_SIGMA 8
#define NBINS   16
#define HDIM    1024
#define WDIM    1024
#define GH      129   // (1024-1)/8 + 2
#define GW      129
#define GZ      17    // NBINS + 1
#define PLANE   (GH*GW)      // 16641 cells per z-plane
#define CELLS   (GH*GW*GZ)   // 282897 cells per image
#define EPSV    1e-8f
#define FIXS    1048576.0f   // 2^20 fixed-point scale
#define FIXI    (1.0f/1048576.0f)

// Grid layout is Z-MAJOR: [b][z][gy][gx] (float2 = val,wt).

// ---- gather splat: 4 threads/cell, fire-and-forget ds_add_u32 (r12) ----
__global__ __launch_bounds__(256) void splat_gather_kernel(
    const float* __restrict__ img, float* __restrict__ grid, int nImg, int imgBase)
{
    __shared__ unsigned lval[16 * 64];   // [gz][cell], bank = cell%32
    __shared__ unsigned lwt [16 * 64];

    int tid = threadIdx.x;
    int c   = tid & 63;
    int q   = tid >> 6;
    int cellIdx = blockIdx.x * 64 + c;
    int total = nImg * PLANE;

    for (int i = tid; i < 16 * 64; i += 256) { lval[i] = 0u; lwt[i] = 0u; }
    __syncthreads();

    if (cellIdx < total) {
        int b   = cellIdx / PLANE;
        int rem = cellIdx - b * PLANE;
        int gy  = rem / GW;
        int gx  = rem - gy * GW;
        const float* ib = img + (size_t)(imgBase + b) * (HDIM * WDIM);

        bool interior = (gx >= 1) & (gx <= 127) & (gy >= 1) & (gy <= 127);
        if (interior) {
            int py = gy & 1, px = gx & 1;
            int ylo = 8 * gy - 4 + py;
            int nr  = 9 - 2 * py;
            int ax  = 8 * gx - 4;
            for (int r = q; r < nr; r += 4) {
                const float* rp = ib + (size_t)(ylo + r) * WDIM + ax;
                float4 A = *(const float4*)rp;
                float4 B = *(const float4*)(rp + 4);
                float  cv = rp[8];
                float e7[7] = {A.y, A.z, A.w, B.x, B.y, B.z, B.w};
                #pragma unroll
                for (int j = 0; j < 7; ++j) {
                    float v = e7[j];
                    int gz = min(max((int)rintf(v * 15.0f), 0), 15);
                    atomicAdd(&lval[gz * 64 + c], (unsigned)rintf(v * FIXS));
                    atomicAdd(&lwt [gz * 64 + c], 1u);
                }
                if (!px) {
                    int gz = min(max((int)rintf(A.x * 15.0f), 0), 15);
                    atomicAdd(&lval[gz * 64 + c], (unsigned)rintf(A.x * FIXS));
                    atomicAdd(&lwt [gz * 64 + c], 1u);
                    gz = min(max((int)rintf(cv * 15.0f), 0), 15);
                    atomicAdd(&lval[gz * 64 + c], (unsigned)rintf(cv * FIXS));
                    atomicAdd(&lwt [gz * 64 + c], 1u);
                }
            }
        } else {
            int ylo = max(0, 8 * gy - 4 + (gy & 1));
            int yhi = min(HDIM - 1, 8 * gy + 4 - (gy & 1));
            int xlo = max(0, 8 * gx - 4 + (gx & 1));
            int xhi = min(WDIM - 1, 8 * gx + 4 - (gx & 1));
            for (int y = ylo + q; y <= yhi; y += 4) {
                const float* row = ib + (size_t)y * WDIM;
                for (int x = xlo; x <= xhi; ++x) {
                    float v = row[x];
                    int gz = min(max((int)rintf(v * 15.0f), 0), 15);
                    atomicAdd(&lval[gz * 64 + c], (unsigned)rintf(v * FIXS));
                    atomicAdd(&lwt [gz * 64 + c], 1u);
                }
            }
        }
    }
    __syncthreads();

    // z-major writeout: lane c consecutive spatial -> 512B runs per z-plane
    if (cellIdx < total) {
        int b   = cellIdx / PLANE;
        int sp  = cellIdx - b * PLANE;
        float2* dstb = (float2*)grid + (size_t)b * CELLS + sp;
        int zlo = q * 4;
        int zhi = (q == 3) ? 17 : zlo + 4;
        for (int z = zlo; z < zhi; ++z) {
            float2 o;
            if (z == 16) { o.x = 0.f; o.y = 0.f; }
            else {
                o.x = (float)lval[z * 64 + c] * FIXI;
                o.y = (float)lwt [z * 64 + c];
            }
            dstb[(size_t)z * PLANE] = o;
        }
    }
}

// ---- blur pass: element-parallel streaming, z-major, no LDS ----
// AX: 0=y (stride GW), 1=x (stride 1), 2=z (stride PLANE). Zero pad.
template <int AX>
__global__ __launch_bounds__(256) void blur_pass(
    const float2* __restrict__ in, float2* __restrict__ out,
    const float* __restrict__ kf)
{
    int idx = blockIdx.x * 256 + threadIdx.x;
    if (idx >= CELLS) return;
    int b   = blockIdx.y;
    int z   = idx / PLANE;
    int rem = idx - z * PLANE;
    int gy  = rem / GW;
    int gx  = rem - gy * GW;

    float kk[5] = {kf[0], kf[1], kf[2], kf[3], kf[4]};
    int c      = (AX == 0) ? gy : (AX == 1) ? gx : z;
    int extent = (AX == 0) ? GH : (AX == 1) ? GW : GZ;
    int stride = (AX == 0) ? GW : (AX == 1) ? 1  : PLANE;

    const float2* p = in + (size_t)b * CELLS + idx;
    float2 a; a.x = 0.f; a.y = 0.f;
    #pragma unroll
    for (int t = 0; t < 5; ++t) {
        int cc = c + t - 2;
        if (cc >= 0 && cc < extent) {
            float2 g = p[(t - 2) * stride];
            a.x += kk[t] * g.x;
            a.y += kk[t] * g.y;
        }
    }
    out[(size_t)b * CELLS + idx] = a;
}

// ---- slice: grid rows k,k+1 in LDS as [z][r][x0pad] (conflict-free) ----
// z-major global: rows k,k+1 of plane z are one contiguous 258-f2 run.
#define XP2   136
#define RST   XP2
#define ZST   (2*XP2)

__global__ __launch_bounds__(256) void slice_rows_kernel(
    const float* __restrict__ img, const float2* __restrict__ grid,
    float* __restrict__ out, int imgBase)
{
    __shared__ float2 sg[GZ * ZST];   // 36992 B

    int tid = threadIdx.x;
    int k   = blockIdx.x;    // 0..127 (8-pixel-row group)
    int b   = blockIdx.y;

    const float2* gsrc = grid + (size_t)b * CELLS + (size_t)k * GW;
    for (int i = tid; i < GZ * 2 * GW; i += 256) {
        int z   = i / (2 * GW);
        int off = i - z * (2 * GW);          // 0..257 over rows k,k+1
        float2 g = gsrc[(size_t)z * PLANE + off];
        int r  = off >= GW ? 1 : 0;
        int x0 = off - r * GW;
        sg[z * ZST + r * RST + x0] = g;
    }
    __syncthreads();

    int x   = tid << 2;
    int x0v = tid >> 1;
    float txb = (float)(x & 7) * 0.125f;

    size_t rowBase = (size_t)(imgBase + b) * (HDIM * WDIM) + (size_t)(k << 3) * WDIM + x;

    #pragma unroll
    for (int r = 0; r < 8; ++r) {
        size_t pixBase = rowBase + (size_t)r * WDIM;
        float4 v4 = *(const float4*)(img + pixBase);
        float ty = (float)r * 0.125f;
        float wy0 = 1.f - ty, wy1 = ty;

        float vv[4] = {v4.x, v4.y, v4.z, v4.w};
        float rr[4];
        #pragma unroll
        for (int j = 0; j < 4; ++j) {
            float v  = vv[j];
            float fz = fminf(fmaxf(v * 15.0f, 0.0f), 15.0f);
            float zf = floorf(fz);
            int   z0 = (int)zf;
            float tz = fz - zf;
            float tx = txb + (float)j * 0.125f;
            float wx0 = 1.f - tx, wx1 = tx;
            float wz0 = 1.f - tz, wz1 = tz;

            int base = z0 * ZST + x0v;
            float2 g000 = sg[base];
            float2 g010 = sg[base + 1];
            float2 g100 = sg[base + RST];
            float2 g110 = sg[base + RST + 1];
            float2 g001 = sg[base + ZST];
            float2 g011 = sg[base + ZST + 1];
            float2 g101 = sg[base + ZST + RST];
            float2 g111 = sg[base + ZST + RST + 1];

            float ov = 0.f, ow = 0.f, w;
            w = wy0 * wx0 * wz0; ov += w * g000.x; ow += w * g000.y;
            w = wy0 * wx0 * wz1; ov += w * g001.x; ow += w * g001.y;
            w = wy0 * wx1 * wz0; ov += w * g010.x; ow += w * g010.y;
            w = wy0 * wx1 * wz1; ov += w * g011.x; ow += w * g011.y;
            w = wy1 * wx0 * wz0; ov += w * g100.x; ow += w * g100.y;
            w = wy1 * wx0 * wz1; ov += w * g101.x; ow += w * g101.y;
            w = wy1 * wx1 * wz0; ov += w * g110.x; ow += w * g110.y;
            w = wy1 * wx1 * wz1; ov += w * g111.x; ow += w * g111.y;
            rr[j] = ov / (ow + EPSV);
        }
        float4 r4; r4.x = rr[0]; r4.y = rr[1]; r4.z = rr[2]; r4.w = rr[3];
        *(float4*)(out + pixBase) = r4;
    }
}

extern "C" void kernel_launch(void* const* d_in, const int* in_sizes, int n_in,
                              void* d_out, int out_size, void* d_ws, size_t ws_size,
                              hipStream_t stream)
{
    const float* img = (const float*)d_in[0];
    const float* fs  = (const float*)d_in[2];
    const float* fr  = (const float*)d_in[3];
    float* out = (float*)d_out;

    int nImgTotal = in_sizes[0] / (HDIM * WDIM);   // 12
    size_t perImgBytes = (size_t)CELLS * 2 * sizeof(float);

    int maxChunk = (int)(ws_size / (2 * perImgBytes));
    if (maxChunk < 1) return;
    if (maxChunk > nImgTotal) maxChunk = nImgTotal;

    for (int base = 0; base < nImgTotal; base += maxChunk) {
        int c = nImgTotal - base;
        if (c > maxChunk) c = maxChunk;

        float* A = (float*)d_ws;
        float* B = A + (size_t)c * CELLS * 2;

        int nCells = c * PLANE;
        int cellBlocks = (nCells + 63) / 64;
        splat_gather_kernel<<<cellBlocks, 256, 0, stream>>>(img, A, c, base);

        int eBlocks = (CELLS + 255) / 256;          // 1106
        dim3 bgrid(eBlocks, c);
        blur_pass<0><<<bgrid, 256, 0, stream>>>((const float2*)A, (float2*)B, fs);
        blur_pass<1><<<bgrid, 256, 0, stream>>>((const float2*)B, (float2*)A, fs);
        blur_pass<2><<<bgrid, 256, 0, stream>>>((const float2*)A, (float2*)B, fr);

        dim3 sgrid(HDIM / 8, c);
        slice_rows_kernel<<<sgrid, 256, 0, stream>>>(img, (const float2*)B, out, base);
    }
}

// Round 18
// 98.136 us; speedup vs baseline: 1.2259x; 1.2259x over previous
//
#include <hip/hip_runtime.h>

#define S_SIGMA 8
#define NBINS   16
#define HDIM    1024
#define WDIM    1024
#define GH      129   // (1024-1)/8 + 2
#define GW      129
#define GZ      17    // NBINS + 1
#define CELLS   (GH*GW*GZ)   // 282897 cells per image
#define ROWSZ   (GW*GZ)      // 2193 float2 per grid row
#define EPSV    1e-8f
#define FIXS    1048576.0f   // 2^20 fixed-point scale
#define FIXI    (1.0f/1048576.0f)

// Grid A layout: [b][gy][gx][z].  Grid B (blurred): [b][gy][z][gx].

// ---- gather splat (r12, best measured): 4 threads/cell, ds_add_u32 ----
__global__ __launch_bounds__(256) void splat_gather_kernel(
    const float* __restrict__ img, float* __restrict__ grid, int nImg, int imgBase)
{
    __shared__ unsigned lval[16 * 64];   // [gz][cell], bank = cell%32
    __shared__ unsigned lwt [16 * 64];

    int tid = threadIdx.x;
    int c   = tid & 63;
    int q   = tid >> 6;
    int cellIdx = blockIdx.x * 64 + c;
    int total = nImg * GH * GW;

    for (int i = tid; i < 16 * 64; i += 256) { lval[i] = 0u; lwt[i] = 0u; }
    __syncthreads();

    if (cellIdx < total) {
        int b   = cellIdx / (GH * GW);
        int rem = cellIdx - b * (GH * GW);
        int gy  = rem / GW;
        int gx  = rem - gy * GW;
        const float* ib = img + (size_t)(imgBase + b) * (HDIM * WDIM);

        bool interior = (gx >= 1) & (gx <= 127) & (gy >= 1) & (gy <= 127);
        if (interior) {
            int py = gy & 1, px = gx & 1;
            int ylo = 8 * gy - 4 + py;
            int nr  = 9 - 2 * py;
            int ax  = 8 * gx - 4;
            for (int r = q; r < nr; r += 4) {
                const float* rp = ib + (size_t)(ylo + r) * WDIM + ax;
                float4 A = *(const float4*)rp;
                float4 B = *(const float4*)(rp + 4);
                float  cv = rp[8];
                float e7[7] = {A.y, A.z, A.w, B.x, B.y, B.z, B.w};
                #pragma unroll
                for (int j = 0; j < 7; ++j) {
                    float v = e7[j];
                    int gz = min(max((int)rintf(v * 15.0f), 0), 15);
                    atomicAdd(&lval[gz * 64 + c], (unsigned)rintf(v * FIXS));
                    atomicAdd(&lwt [gz * 64 + c], 1u);
                }
                if (!px) {
                    int gz = min(max((int)rintf(A.x * 15.0f), 0), 15);
                    atomicAdd(&lval[gz * 64 + c], (unsigned)rintf(A.x * FIXS));
                    atomicAdd(&lwt [gz * 64 + c], 1u);
                    gz = min(max((int)rintf(cv * 15.0f), 0), 15);
                    atomicAdd(&lval[gz * 64 + c], (unsigned)rintf(cv * FIXS));
                    atomicAdd(&lwt [gz * 64 + c], 1u);
                }
            }
        } else {
            int ylo = max(0, 8 * gy - 4 + (gy & 1));
            int yhi = min(HDIM - 1, 8 * gy + 4 - (gy & 1));
            int xlo = max(0, 8 * gx - 4 + (gx & 1));
            int xhi = min(WDIM - 1, 8 * gx + 4 - (gx & 1));
            for (int y = ylo + q; y <= yhi; y += 4) {
                const float* row = ib + (size_t)y * WDIM;
                for (int x = xlo; x <= xhi; ++x) {
                    float v = row[x];
                    int gz = min(max((int)rintf(v * 15.0f), 0), 15);
                    atomicAdd(&lval[gz * 64 + c], (unsigned)rintf(v * FIXS));
                    atomicAdd(&lwt [gz * 64 + c], 1u);
                }
            }
        }
    }
    __syncthreads();

    if (cellIdx < total) {
        float2* dst = (float2*)grid + (size_t)cellIdx * GZ;
        int zlo = q * 4;
        int zhi = (q == 3) ? 17 : zlo + 4;
        for (int z = zlo; z < zhi; ++z) {
            float2 o;
            if (z == 16) { o.x = 0.f; o.y = 0.f; }
            else {
                o.x = (float)lval[z * 64 + c] * FIXI;
                o.y = (float)lwt [z * 64 + c];
            }
            dst[z] = o;
        }
    }
}

// ---- fused blur, z-half split, TO=12, compile-time half H ----
// H=0: out z 0..8  <- in z 0..10 (nzi=11, zbase=0)
// H=1: out z 9..16 <- in z 7..16 (nzi=10, zbase=7)
// LDS 22.5 KB, reg arrays 32 VGPR -> high occupancy. All divides by
// compile-time constants (magic-mul), unlike r13's runtime-nzi mistake.
#define TO 12
#define TI 16

template <int H>
__global__ __launch_bounds__(256, 6) void blur_fused_kernel(
    const float2* __restrict__ in, float2* __restrict__ out,
    const float* __restrict__ kfs, const float* __restrict__ kfr)
{
    constexpr int ZB  = H * 7;           // zbase
    constexpr int NZI = 11 - H;          // input z planes
    constexpr int NZO = 9 - H;           // output z planes
    constexpr int ZOL = 9 * H;           // first output z
    constexpr int NIN  = TI * TI * NZI;
    constexpr int NTMP = TO * TI * NZI;
    constexpr int NX   = TO * TO * NZI;
    constexpr int NOUT = TO * TO * NZO;
    constexpr int NTI  = (NTMP + 255) / 256;   // 9 or 8
    constexpr int NXI  = (NX   + 255) / 256;   // 7 or 6

    __shared__ float2 sbin[TI * TI * 11];      // max size (H=0): 22528 B

    int tid = threadIdx.x;
    int tx0 = blockIdx.x * TO;
    int ty0 = blockIdx.y * TO;
    int b   = blockIdx.z;

    float ks[5] = {kfs[0], kfs[1], kfs[2], kfs[3], kfs[4]};
    float kr[5] = {kfr[0], kfr[1], kfr[2], kfr[3], kfr[4]};

    const float2* gb = in + (size_t)b * CELLS;
    for (int li = tid; li < NIN; li += 256) {
        int iy = li / (TI * NZI);
        int r  = li - iy * (TI * NZI);
        int ix = r / NZI;
        int zi = r - ix * NZI;
        int gy = ty0 - 2 + iy;
        int gx = tx0 - 2 + ix;
        float2 v; v.x = 0.f; v.y = 0.f;
        if (gy >= 0 && gy < GH && gx >= 0 && gx < GW)
            v = gb[((size_t)gy * GW + gx) * GZ + ZB + zi];
        sbin[li] = v;
    }
    __syncthreads();

    // y blur into registers
    float2 rt[NTI];
    #pragma unroll
    for (int it = 0; it < NTI; ++it) {
        int o = tid + it * 256;
        float2 a; a.x = 0.f; a.y = 0.f;
        if (o < NTMP) {
            int oy = o / (TI * NZI);
            int r  = o - oy * (TI * NZI);
            #pragma unroll
            for (int t = 0; t < 5; ++t) {
                float2 g = sbin[(oy + t) * (TI * NZI) + r];
                a.x += ks[t] * g.x;
                a.y += ks[t] * g.y;
            }
        }
        rt[it] = a;
    }
    __syncthreads();
    #pragma unroll
    for (int it = 0; it < NTI; ++it) {
        int o = tid + it * 256;
        if (o < NTMP) sbin[o] = rt[it];        // [oy][ix][zi]
    }
    __syncthreads();

    // x blur into registers
    float2 rx[NXI];
    #pragma unroll
    for (int it = 0; it < NXI; ++it) {
        int o = tid + it * 256;
        float2 a; a.x = 0.f; a.y = 0.f;
        if (o < NX) {
            int oy = o / (TO * NZI);
            int r  = o - oy * (TO * NZI);
            int ox = r / NZI;
            int zi = r - ox * NZI;
            #pragma unroll
            for (int t = 0; t < 5; ++t) {
                float2 g = sbin[oy * (TI * NZI) + (ox + t) * NZI + zi];
                a.x += ks[t] * g.x;
                a.y += ks[t] * g.y;
            }
        }
        rx[it] = a;
    }
    __syncthreads();
    #pragma unroll
    for (int it = 0; it < NXI; ++it) {
        int o = tid + it * 256;
        if (o < NX) sbin[o] = rx[it];          // xb: [oy][ox][zi]
    }
    __syncthreads();

    // z blur + transposed store [gy][z][gx]; (oy, zo, ox) order -> coalesced
    float2* ob = out + (size_t)b * CELLS;
    for (int o = tid; o < NOUT; o += 256) {
        int oy = o / (NZO * TO);
        int r2 = o - oy * (NZO * TO);
        int k  = r2 / TO;
        int ox = r2 - k * TO;
        int zo = ZOL + k;
        int gy = ty0 + oy;
        int gx = tx0 + ox;
        if (gy < GH && gx < GW) {
            int cb = (oy * TO + ox) * NZI;
            float2 a; a.x = 0.f; a.y = 0.f;
            #pragma unroll
            for (int t = 0; t < 5; ++t) {
                int zg = zo + t - 2;
                if (zg >= 0 && zg <= 16) {
                    float2 g = sbin[cb + zg - ZB];
                    a.x += kr[t] * g.x;
                    a.y += kr[t] * g.y;
                }
            }
            ob[((size_t)gy * GZ + zo) * GW + gx] = a;
        }
    }
}

// ---- slice (r12, proven): rows k,k+1 in LDS as [z][r][x0pad] ----
#define XP2   136
#define RST   XP2
#define ZST   (2*XP2)

__global__ __launch_bounds__(256) void slice_rows_kernel(
    const float* __restrict__ img, const float2* __restrict__ grid,
    float* __restrict__ out, int imgBase)
{
    __shared__ float2 sg[GZ * ZST];   // 36992 B

    int tid = threadIdx.x;
    int k   = blockIdx.x;
    int b   = blockIdx.y;

    const float2* gsrc = grid + (size_t)b * CELLS + (size_t)k * ROWSZ;
    for (int i = tid; i < 2 * ROWSZ; i += 256) {
        int r   = i / ROWSZ;
        int rem = i - r * ROWSZ;
        int z   = rem / GW;
        int x0  = rem - z * GW;
        sg[z * ZST + r * RST + x0] = gsrc[i];
    }
    __syncthreads();

    int x   = tid << 2;
    int x0v = tid >> 1;
    float txb = (float)(x & 7) * 0.125f;

    size_t rowBase = (size_t)(imgBase + b) * (HDIM * WDIM) + (size_t)(k << 3) * WDIM + x;

    #pragma unroll
    for (int r = 0; r < 8; ++r) {
        size_t pixBase = rowBase + (size_t)r * WDIM;
        float4 v4 = *(const float4*)(img + pixBase);
        float ty = (float)r * 0.125f;
        float wy0 = 1.f - ty, wy1 = ty;

        float vv[4] = {v4.x, v4.y, v4.z, v4.w};
        float rr[4];
        #pragma unroll
        for (int j = 0; j < 4; ++j) {
            float v  = vv[j];
            float fz = fminf(fmaxf(v * 15.0f, 0.0f), 15.0f);
            float zf = floorf(fz);
            int   z0 = (int)zf;
            float tz = fz - zf;
            float tx = txb + (float)j * 0.125f;
            float wx0 = 1.f - tx, wx1 = tx;
            float wz0 = 1.f - tz, wz1 = tz;

            int base = z0 * ZST + x0v;
            float2 g000 = sg[base];
            float2 g010 = sg[base + 1];
            float2 g100 = sg[base + RST];
            float2 g110 = sg[base + RST + 1];
            float2 g001 = sg[base + ZST];
            float2 g011 = sg[base + ZST + 1];
            float2 g101 = sg[base + ZST + RST];
            float2 g111 = sg[base + ZST + RST + 1];

            float ov = 0.f, ow = 0.f, w;
            w = wy0 * wx0 * wz0; ov += w * g000.x; ow += w * g000.y;
            w = wy0 * wx0 * wz1; ov += w * g001.x; ow += w * g001.y;
            w = wy0 * wx1 * wz0; ov += w * g010.x; ow += w * g010.y;
            w = wy0 * wx1 * wz1; ov += w * g011.x; ow += w * g011.y;
            w = wy1 * wx0 * wz0; ov += w * g100.x; ow += w * g100.y;
            w = wy1 * wx0 * wz1; ov += w * g101.x; ow += w * g101.y;
            w = wy1 * wx1 * wz0; ov += w * g110.x; ow += w * g110.y;
            w = wy1 * wx1 * wz1; ov += w * g111.x; ow += w * g111.y;
            rr[j] = ov / (ow + EPSV);
        }
        float4 r4; r4.x = rr[0]; r4.y = rr[1]; r4.z = rr[2]; r4.w = rr[3];
        *(float4*)(out + pixBase) = r4;
    }
}

extern "C" void kernel_launch(void* const* d_in, const int* in_sizes, int n_in,
                              void* d_out, int out_size, void* d_ws, size_t ws_size,
                              hipStream_t stream)
{
    const float* img = (const float*)d_in[0];
    const float* fs  = (const float*)d_in[2];
    const float* fr  = (const float*)d_in[3];
    float* out = (float*)d_out;

    int nImgTotal = in_sizes[0] / (HDIM * WDIM);   // 12
    size_t perImgBytes = (size_t)CELLS * 2 * sizeof(float);

    int maxChunk = (int)(ws_size / (2 * perImgBytes));
    if (maxChunk < 1) return;
    if (maxChunk > nImgTotal) maxChunk = nImgTotal;

    const int tilesPerDim = (GH + TO - 1) / TO;    // 11

    for (int base = 0; base < nImgTotal; base += maxChunk) {
        int c = nImgTotal - base;
        if (c > maxChunk) c = maxChunk;

        float* A = (float*)d_ws;
        float* B = A + (size_t)c * CELLS * 2;

        int nCells = c * GH * GW;
        int cellBlocks = (nCells + 63) / 64;
        splat_gather_kernel<<<cellBlocks, 256, 0, stream>>>(img, A, c, base);

        dim3 bgrid(tilesPerDim, tilesPerDim, c);
        blur_fused_kernel<0><<<bgrid, 256, 0, stream>>>((const float2*)A, (float2*)B, fs, fr);
        blur_fused_kernel<1><<<bgrid, 256, 0, stream>>>((const float2*)A, (float2*)B, fs, fr);

        dim3 sgrid(HDIM / 8, c);
        slice_rows_kernel<<<sgrid, 256, 0, stream>>>(img, (const float2*)B, out, base);
    }
}

// Round 19
// 96.145 us; speedup vs baseline: 1.2513x; 1.0207x over previous
//
#include <hip/hip_runtime.h>

#define S_SIGMA 8
#define NBINS   16
#define HDIM    1024
#define WDIM    1024
#define GH      129   // (1024-1)/8 + 2
#define GW      129
#define GZ      17    // NBINS + 1
#define CELLS   (GH*GW*GZ)   // 282897 cells per image
#define ROWSZ   (GW*GZ)      // 2193 float2 per grid row
#define EPSV    1e-8f
#define FIXS    1048576.0f   // 2^20 fixed-point scale
#define FIXI    (1.0f/1048576.0f)

// Grid A: [b][gy][gx][z].  After blur: [b][gy][z][gx].

// ---- gather splat: 8 threads/cell, fire-and-forget ds_add_u32 ----
// 32 cells per 256-thread block; thread h owns rows h, h+8 of the cell's
// footprint (<=2 rows). Shorter chains + more blocks than r12's 4-thread.
__global__ __launch_bounds__(256) void splat_gather_kernel(
    const float* __restrict__ img, float* __restrict__ grid, int nImg, int imgBase)
{
    __shared__ unsigned lval[16 * 32];   // [gz][cell], bank = cell
    __shared__ unsigned lwt [16 * 32];

    int tid = threadIdx.x;
    int c   = tid & 31;
    int h   = tid >> 5;          // 0..7
    int cellIdx = blockIdx.x * 32 + c;
    int total = nImg * GH * GW;

    for (int i = tid; i < 16 * 32; i += 256) { lval[i] = 0u; lwt[i] = 0u; }
    __syncthreads();

    if (cellIdx < total) {
        int b   = cellIdx / (GH * GW);
        int rem = cellIdx - b * (GH * GW);
        int gy  = rem / GW;
        int gx  = rem - gy * GW;
        const float* ib = img + (size_t)(imgBase + b) * (HDIM * WDIM);

        bool interior = (gx >= 1) & (gx <= 127) & (gy >= 1) & (gy <= 127);
        if (interior) {
            int py = gy & 1, px = gx & 1;
            int ylo = 8 * gy - 4 + py;
            int nr  = 9 - 2 * py;
            int ax  = 8 * gx - 4;
            for (int r = h; r < nr; r += 8) {
                const float* rp = ib + (size_t)(ylo + r) * WDIM + ax;
                float4 A = *(const float4*)rp;
                float4 B = *(const float4*)(rp + 4);
                float  cv = rp[8];
                float e7[7] = {A.y, A.z, A.w, B.x, B.y, B.z, B.w};
                #pragma unroll
                for (int j = 0; j < 7; ++j) {
                    float v = e7[j];
                    int gz = min(max((int)rintf(v * 15.0f), 0), 15);
                    atomicAdd(&lval[gz * 32 + c], (unsigned)rintf(v * FIXS));
                    atomicAdd(&lwt [gz * 32 + c], 1u);
                }
                if (!px) {
                    int gz = min(max((int)rintf(A.x * 15.0f), 0), 15);
                    atomicAdd(&lval[gz * 32 + c], (unsigned)rintf(A.x * FIXS));
                    atomicAdd(&lwt [gz * 32 + c], 1u);
                    gz = min(max((int)rintf(cv * 15.0f), 0), 15);
                    atomicAdd(&lval[gz * 32 + c], (unsigned)rintf(cv * FIXS));
                    atomicAdd(&lwt [gz * 32 + c], 1u);
                }
            }
        } else {
            int ylo = max(0, 8 * gy - 4 + (gy & 1));
            int yhi = min(HDIM - 1, 8 * gy + 4 - (gy & 1));
            int xlo = max(0, 8 * gx - 4 + (gx & 1));
            int xhi = min(WDIM - 1, 8 * gx + 4 - (gx & 1));
            for (int y = ylo + h; y <= yhi; y += 8) {
                const float* row = ib + (size_t)y * WDIM;
                for (int x = xlo; x <= xhi; ++x) {
                    float v = row[x];
                    int gz = min(max((int)rintf(v * 15.0f), 0), 15);
                    atomicAdd(&lval[gz * 32 + c], (unsigned)rintf(v * FIXS));
                    atomicAdd(&lwt [gz * 32 + c], 1u);
                }
            }
        }
    }
    __syncthreads();

    // writeout: thread h writes z in {2h, 2h+1} (+ z=16 for h==7)
    if (cellIdx < total) {
        float2* dst = (float2*)grid + (size_t)cellIdx * GZ;
        int zlo = 2 * h;
        int zhi = (h == 7) ? 17 : zlo + 2;
        for (int z = zlo; z < zhi; ++z) {
            float2 o;
            if (z == 16) { o.x = 0.f; o.y = 0.f; }
            else {
                o.x = (float)lval[z * 32 + c] * FIXI;
                o.y = (float)lwt [z * 32 + c];
            }
            dst[z] = o;
        }
    }
}

// ---- y-blur: element-parallel streaming, fully coalesced (r14-proven) ----
__global__ __launch_bounds__(256) void blur_y_row(
    const float2* __restrict__ in, float2* __restrict__ out,
    const float* __restrict__ kfs)
{
    int i  = blockIdx.x * 256 + threadIdx.x;    // 0..ROWSZ-1
    if (i >= ROWSZ) return;
    int gy = blockIdx.y;
    int b  = blockIdx.z;

    float ks[5] = {kfs[0], kfs[1], kfs[2], kfs[3], kfs[4]};

    const float2* gb = in + (size_t)b * CELLS + i;
    float2 a; a.x = 0.f; a.y = 0.f;
    #pragma unroll
    for (int t = 0; t < 5; ++t) {
        int yy = gy + t - 2;
        if (yy >= 0 && yy < GH) {
            float2 g = gb[(size_t)yy * ROWSZ];
            a.x += ks[t] * g.x;
            a.y += ks[t] * g.y;
        }
    }
    out[(size_t)b * CELLS + (size_t)gy * ROWSZ + i] = a;
}

// ---- x+z blur: one block per grid row, LDS-staged, element-parallel ----
// Stage row (17.5 KB) -> x-blur into registers -> write back -> z-blur ->
// transposed store [gy][z][gx]. All LDS patterns conflict-free.
#define NRI 9   // ceil(2193/256)

__global__ __launch_bounds__(256) void blur_xz_row(
    const float2* __restrict__ in, float2* __restrict__ out,
    const float* __restrict__ kfs, const float* __restrict__ kfr)
{
    __shared__ float2 sbin[ROWSZ];   // 17544 B

    int tid = threadIdx.x;
    int gy  = blockIdx.x;
    int b   = blockIdx.y;

    float ks[5] = {kfs[0], kfs[1], kfs[2], kfs[3], kfs[4]};
    float kr[5] = {kfr[0], kfr[1], kfr[2], kfr[3], kfr[4]};

    const float2* gsrc = in + (size_t)b * CELLS + (size_t)gy * ROWSZ;
    for (int i = tid; i < ROWSZ; i += 256) sbin[i] = gsrc[i];
    __syncthreads();

    // x blur into registers; o = gx*17 + z, reads at o + (t-2)*17 (lane-consecutive)
    float2 rt[NRI];
    #pragma unroll
    for (int it = 0; it < NRI; ++it) {
        int o = tid + it * 256;
        float2 a; a.x = 0.f; a.y = 0.f;
        if (o < ROWSZ) {
            int gx = o / GZ;
            #pragma unroll
            for (int t = 0; t < 5; ++t) {
                int xx = gx + t - 2;
                if (xx >= 0 && xx < GW) {
                    float2 g = sbin[o + (t - 2) * GZ];
                    a.x += ks[t] * g.x;
                    a.y += ks[t] * g.y;
                }
            }
        }
        rt[it] = a;
    }
    __syncthreads();
    #pragma unroll
    for (int it = 0; it < NRI; ++it) {
        int o = tid + it * 256;
        if (o < ROWSZ) sbin[o] = rt[it];   // sbin = x-blurred [gx][z]
    }
    __syncthreads();

    // z blur + transposed store; o2 = z*129+gx -> coalesced 1KB row writes;
    // LDS reads at gx*17 + zz: stride 17 (odd) -> bijective banks.
    float2* ob = out + (size_t)b * CELLS + (size_t)gy * ROWSZ;
    for (int o2 = tid; o2 < ROWSZ; o2 += 256) {
        int z  = o2 / GW;
        int gx = o2 - z * GW;
        float2 a; a.x = 0.f; a.y = 0.f;
        #pragma unroll
        for (int t = 0; t < 5; ++t) {
            int zz = z + t - 2;
            if (zz >= 0 && zz < GZ) {
                float2 g = sbin[gx * GZ + zz];
                a.x += kr[t] * g.x;
                a.y += kr[t] * g.y;
            }
        }
        ob[o2] = a;
    }
}

// ---- slice (r12, proven): rows k,k+1 in LDS as [z][r][x0pad] ----
#define XP2   136
#define RST   XP2
#define ZST   (2*XP2)

__global__ __launch_bounds__(256) void slice_rows_kernel(
    const float* __restrict__ img, const float2* __restrict__ grid,
    float* __restrict__ out, int imgBase)
{
    __shared__ float2 sg[GZ * ZST];   // 36992 B

    int tid = threadIdx.x;
    int k   = blockIdx.x;
    int b   = blockIdx.y;

    const float2* gsrc = grid + (size_t)b * CELLS + (size_t)k * ROWSZ;
    for (int i = tid; i < 2 * ROWSZ; i += 256) {
        int r   = i / ROWSZ;
        int rem = i - r * ROWSZ;
        int z   = rem / GW;
        int x0  = rem - z * GW;
        sg[z * ZST + r * RST + x0] = gsrc[i];
    }
    __syncthreads();

    int x   = tid << 2;
    int x0v = tid >> 1;
    float txb = (float)(x & 7) * 0.125f;

    size_t rowBase = (size_t)(imgBase + b) * (HDIM * WDIM) + (size_t)(k << 3) * WDIM + x;

    #pragma unroll
    for (int r = 0; r < 8; ++r) {
        size_t pixBase = rowBase + (size_t)r * WDIM;
        float4 v4 = *(const float4*)(img + pixBase);
        float ty = (float)r * 0.125f;
        float wy0 = 1.f - ty, wy1 = ty;

        float vv[4] = {v4.x, v4.y, v4.z, v4.w};
        float rr[4];
        #pragma unroll
        for (int j = 0; j < 4; ++j) {
            float v  = vv[j];
            float fz = fminf(fmaxf(v * 15.0f, 0.0f), 15.0f);
            float zf = floorf(fz);
            int   z0 = (int)zf;
            float tz = fz - zf;
            float tx = txb + (float)j * 0.125f;
            float wx0 = 1.f - tx, wx1 = tx;
            float wz0 = 1.f - tz, wz1 = tz;

            int base = z0 * ZST + x0v;
            float2 g000 = sg[base];
            float2 g010 = sg[base + 1];
            float2 g100 = sg[base + RST];
            float2 g110 = sg[base + RST + 1];
            float2 g001 = sg[base + ZST];
            float2 g011 = sg[base + ZST + 1];
            float2 g101 = sg[base + ZST + RST];
            float2 g111 = sg[base + ZST + RST + 1];

            float ov = 0.f, ow = 0.f, w;
            w = wy0 * wx0 * wz0; ov += w * g000.x; ow += w * g000.y;
            w = wy0 * wx0 * wz1; ov += w * g001.x; ow += w * g001.y;
            w = wy0 * wx1 * wz0; ov += w * g010.x; ow += w * g010.y;
            w = wy0 * wx1 * wz1; ov += w * g011.x; ow += w * g011.y;
            w = wy1 * wx0 * wz0; ov += w * g100.x; ow += w * g100.y;
            w = wy1 * wx0 * wz1; ov += w * g101.x; ow += w * g101.y;
            w = wy1 * wx1 * wz0; ov += w * g110.x; ow += w * g110.y;
            w = wy1 * wx1 * wz1; ov += w * g111.x; ow += w * g111.y;
            rr[j] = ov / (ow + EPSV);
        }
        float4 r4; r4.x = rr[0]; r4.y = rr[1]; r4.z = rr[2]; r4.w = rr[3];
        *(float4*)(out + pixBase) = r4;
    }
}

extern "C" void kernel_launch(void* const* d_in, const int* in_sizes, int n_in,
                              void* d_out, int out_size, void* d_ws, size_t ws_size,
                              hipStream_t stream)
{
    const float* img = (const float*)d_in[0];
    const float* fs  = (const float*)d_in[2];
    const float* fr  = (const float*)d_in[3];
    float* out = (float*)d_out;

    int nImgTotal = in_sizes[0] / (HDIM * WDIM);   // 12
    size_t perImgBytes = (size_t)CELLS * 2 * sizeof(float);

    int maxChunk = (int)(ws_size / (2 * perImgBytes));
    if (maxChunk < 1) return;
    if (maxChunk > nImgTotal) maxChunk = nImgTotal;

    for (int base = 0; base < nImgTotal; base += maxChunk) {
        int c = nImgTotal - base;
        if (c > maxChunk) c = maxChunk;

        float* A = (float*)d_ws;
        float* B = A + (size_t)c * CELLS * 2;

        int nCells = c * GH * GW;
        int cellBlocks = (nCells + 31) / 32;   // 32 cells per 256-thread block
        splat_gather_kernel<<<cellBlocks, 256, 0, stream>>>(img, A, c, base);

        dim3 ygrid((ROWSZ + 255) / 256, GH, c);    // 9 x 129 x c
        blur_y_row<<<ygrid, 256, 0, stream>>>((const float2*)A, (float2*)B, fs);

        dim3 xzgrid(GH, c);                        // 129 x c row blocks
        blur_xz_row<<<xzgrid, 256, 0, stream>>>((const float2*)B, (float2*)A, fs, fr);

        dim3 sgrid(HDIM / 8, c);
        slice_rows_kernel<<<sgrid, 256, 0, stream>>>(img, (const float2*)A, out, base);
    }
}

// Round 20
// 92.308 us; speedup vs baseline: 1.3033x; 1.0416x over previous
//
#include <hip/hip_runtime.h>

#define S_SIGMA 8
#define NBINS   16
#define HDIM    1024
#define WDIM    1024
#define GH      129   // (1024-1)/8 + 2
#define GW      129
#define GZ      17    // NBINS + 1
#define CELLS   (GH*GW*GZ)   // 282897 cells per image
#define ROWSZ   (GW*GZ)      // 2193 float2 per grid row
#define EPSV    1e-8f
#define FIXS    1048576.0f   // 2^20 fixed-point scale
#define FIXI    (1.0f/1048576.0f)

// Grid A: [b][gy][gx][z].  Grid B (blurred): [b][gy][z][gx].

// ---- gather splat (r12, proven best): 4 threads/cell, ds_add_u32 ----
__global__ __launch_bounds__(256) void splat_gather_kernel(
    const float* __restrict__ img, float* __restrict__ grid, int nImg, int imgBase)
{
    __shared__ unsigned lval[16 * 64];   // [gz][cell], bank = cell%32
    __shared__ unsigned lwt [16 * 64];

    int tid = threadIdx.x;
    int c   = tid & 63;
    int q   = tid >> 6;
    int cellIdx = blockIdx.x * 64 + c;
    int total = nImg * GH * GW;

    for (int i = tid; i < 16 * 64; i += 256) { lval[i] = 0u; lwt[i] = 0u; }
    __syncthreads();

    if (cellIdx < total) {
        int b   = cellIdx / (GH * GW);
        int rem = cellIdx - b * (GH * GW);
        int gy  = rem / GW;
        int gx  = rem - gy * GW;
        const float* ib = img + (size_t)(imgBase + b) * (HDIM * WDIM);

        bool interior = (gx >= 1) & (gx <= 127) & (gy >= 1) & (gy <= 127);
        if (interior) {
            int py = gy & 1, px = gx & 1;
            int ylo = 8 * gy - 4 + py;
            int nr  = 9 - 2 * py;
            int ax  = 8 * gx - 4;
            for (int r = q; r < nr; r += 4) {
                const float* rp = ib + (size_t)(ylo + r) * WDIM + ax;
                float4 A = *(const float4*)rp;
                float4 B = *(const float4*)(rp + 4);
                float  cv = rp[8];
                float e7[7] = {A.y, A.z, A.w, B.x, B.y, B.z, B.w};
                #pragma unroll
                for (int j = 0; j < 7; ++j) {
                    float v = e7[j];
                    int gz = min(max((int)rintf(v * 15.0f), 0), 15);
                    atomicAdd(&lval[gz * 64 + c], (unsigned)rintf(v * FIXS));
                    atomicAdd(&lwt [gz * 64 + c], 1u);
                }
                if (!px) {
                    int gz = min(max((int)rintf(A.x * 15.0f), 0), 15);
                    atomicAdd(&lval[gz * 64 + c], (unsigned)rintf(A.x * FIXS));
                    atomicAdd(&lwt [gz * 64 + c], 1u);
                    gz = min(max((int)rintf(cv * 15.0f), 0), 15);
                    atomicAdd(&lval[gz * 64 + c], (unsigned)rintf(cv * FIXS));
                    atomicAdd(&lwt [gz * 64 + c], 1u);
                }
            }
        } else {
            int ylo = max(0, 8 * gy - 4 + (gy & 1));
            int yhi = min(HDIM - 1, 8 * gy + 4 - (gy & 1));
            int xlo = max(0, 8 * gx - 4 + (gx & 1));
            int xhi = min(WDIM - 1, 8 * gx + 4 - (gx & 1));
            for (int y = ylo + q; y <= yhi; y += 4) {
                const float* row = ib + (size_t)y * WDIM;
                for (int x = xlo; x <= xhi; ++x) {
                    float v = row[x];
                    int gz = min(max((int)rintf(v * 15.0f), 0), 15);
                    atomicAdd(&lval[gz * 64 + c], (unsigned)rintf(v * FIXS));
                    atomicAdd(&lwt [gz * 64 + c], 1u);
                }
            }
        }
    }
    __syncthreads();

    if (cellIdx < total) {
        float2* dst = (float2*)grid + (size_t)cellIdx * GZ;
        int zlo = q * 4;
        int zhi = (q == 3) ? 17 : zlo + 4;
        for (int z = zlo; z < zhi; ++z) {
            float2 o;
            if (z == 16) { o.x = 0.f; o.y = 0.f; }
            else {
                o.x = (float)lval[z * 64 + c] * FIXI;
                o.y = (float)lwt [z * 64 + c];
            }
            dst[z] = o;
        }
    }
}

// ---- single-pass blur: y-taps applied during staging, then x,z in LDS ----
// One block per (gy, b). Grid A rows gy-2..gy+2 are L3-resident (27 MB grid),
// so the 5x row re-read costs no extra HBM fetch. All LDS patterns
// conflict-free (r18-verified): x-blur reads lane-consecutive +-17*t; z-blur
// reads stride-17 (odd -> bijective banks); writes linear.
#define NRI 9   // ceil(2193/256)

__global__ __launch_bounds__(256) void blur_yxz_row(
    const float2* __restrict__ in, float2* __restrict__ out,
    const float* __restrict__ kfs, const float* __restrict__ kfr)
{
    __shared__ float2 sbin[ROWSZ];   // 17544 B

    int tid = threadIdx.x;
    int gy  = blockIdx.x;
    int b   = blockIdx.y;

    float ks[5] = {kfs[0], kfs[1], kfs[2], kfs[3], kfs[4]};
    float kr[5] = {kfr[0], kfr[1], kfr[2], kfr[3], kfr[4]};

    // stage row gy with the 5-tap y-blur applied on the fly
    const float2* gb = in + (size_t)b * CELLS;
    int ylo = max(0, gy - 2), yhi = min(GH - 1, gy + 2);
    for (int i = tid; i < ROWSZ; i += 256) {
        float2 a; a.x = 0.f; a.y = 0.f;
        for (int yy = ylo; yy <= yhi; ++yy) {
            float k = ks[yy - gy + 2];
            float2 g = gb[(size_t)yy * ROWSZ + i];
            a.x += k * g.x;
            a.y += k * g.y;
        }
        sbin[i] = a;
    }
    __syncthreads();

    // x blur into registers; o = gx*17 + z, reads at o + (t-2)*17
    float2 rt[NRI];
    #pragma unroll
    for (int it = 0; it < NRI; ++it) {
        int o = tid + it * 256;
        float2 a; a.x = 0.f; a.y = 0.f;
        if (o < ROWSZ) {
            int gx = o / GZ;
            #pragma unroll
            for (int t = 0; t < 5; ++t) {
                int xx = gx + t - 2;
                if (xx >= 0 && xx < GW) {
                    float2 g = sbin[o + (t - 2) * GZ];
                    a.x += ks[t] * g.x;
                    a.y += ks[t] * g.y;
                }
            }
        }
        rt[it] = a;
    }
    __syncthreads();
    #pragma unroll
    for (int it = 0; it < NRI; ++it) {
        int o = tid + it * 256;
        if (o < ROWSZ) sbin[o] = rt[it];   // sbin = yx-blurred [gx][z]
    }
    __syncthreads();

    // z blur + transposed store [gy][z][gx]; coalesced 1KB row writes
    float2* ob = out + (size_t)b * CELLS + (size_t)gy * ROWSZ;
    for (int o2 = tid; o2 < ROWSZ; o2 += 256) {
        int z  = o2 / GW;
        int gx = o2 - z * GW;
        float2 a; a.x = 0.f; a.y = 0.f;
        #pragma unroll
        for (int t = 0; t < 5; ++t) {
            int zz = z + t - 2;
            if (zz >= 0 && zz < GZ) {
                float2 g = sbin[gx * GZ + zz];
                a.x += kr[t] * g.x;
                a.y += kr[t] * g.y;
            }
        }
        ob[o2] = a;
    }
}

// ---- slice (r12, proven): rows k,k+1 in LDS as [z][r][x0pad] ----
#define XP2   136
#define RST   XP2
#define ZST   (2*XP2)

__global__ __launch_bounds__(256) void slice_rows_kernel(
    const float* __restrict__ img, const float2* __restrict__ grid,
    float* __restrict__ out, int imgBase)
{
    __shared__ float2 sg[GZ * ZST];   // 36992 B

    int tid = threadIdx.x;
    int k   = blockIdx.x;
    int b   = blockIdx.y;

    const float2* gsrc = grid + (size_t)b * CELLS + (size_t)k * ROWSZ;
    for (int i = tid; i < 2 * ROWSZ; i += 256) {
        int r   = i / ROWSZ;
        int rem = i - r * ROWSZ;
        int z   = rem / GW;
        int x0  = rem - z * GW;
        sg[z * ZST + r * RST + x0] = gsrc[i];
    }
    __syncthreads();

    int x   = tid << 2;
    int x0v = tid >> 1;
    float txb = (float)(x & 7) * 0.125f;

    size_t rowBase = (size_t)(imgBase + b) * (HDIM * WDIM) + (size_t)(k << 3) * WDIM + x;

    #pragma unroll
    for (int r = 0; r < 8; ++r) {
        size_t pixBase = rowBase + (size_t)r * WDIM;
        float4 v4 = *(const float4*)(img + pixBase);
        float ty = (float)r * 0.125f;
        float wy0 = 1.f - ty, wy1 = ty;

        float vv[4] = {v4.x, v4.y, v4.z, v4.w};
        float rr[4];
        #pragma unroll
        for (int j = 0; j < 4; ++j) {
            float v  = vv[j];
            float fz = fminf(fmaxf(v * 15.0f, 0.0f), 15.0f);
            float zf = floorf(fz);
            int   z0 = (int)zf;
            float tz = fz - zf;
            float tx = txb + (float)j * 0.125f;
            float wx0 = 1.f - tx, wx1 = tx;
            float wz0 = 1.f - tz, wz1 = tz;

            int base = z0 * ZST + x0v;
            float2 g000 = sg[base];
            float2 g010 = sg[base + 1];
            float2 g100 = sg[base + RST];
            float2 g110 = sg[base + RST + 1];
            float2 g001 = sg[base + ZST];
            float2 g011 = sg[base + ZST + 1];
            float2 g101 = sg[base + ZST + RST];
            float2 g111 = sg[base + ZST + RST + 1];

            float ov = 0.f, ow = 0.f, w;
            w = wy0 * wx0 * wz0; ov += w * g000.x; ow += w * g000.y;
            w = wy0 * wx0 * wz1; ov += w * g001.x; ow += w * g001.y;
            w = wy0 * wx1 * wz0; ov += w * g010.x; ow += w * g010.y;
            w = wy0 * wx1 * wz1; ov += w * g011.x; ow += w * g011.y;
            w = wy1 * wx0 * wz0; ov += w * g100.x; ow += w * g100.y;
            w = wy1 * wx0 * wz1; ov += w * g101.x; ow += w * g101.y;
            w = wy1 * wx1 * wz0; ov += w * g110.x; ow += w * g110.y;
            w = wy1 * wx1 * wz1; ov += w * g111.x; ow += w * g111.y;
            rr[j] = ov / (ow + EPSV);
        }
        float4 r4; r4.x = rr[0]; r4.y = rr[1]; r4.z = rr[2]; r4.w = rr[3];
        *(float4*)(out + pixBase) = r4;
    }
}

extern "C" void kernel_launch(void* const* d_in, const int* in_sizes, int n_in,
                              void* d_out, int out_size, void* d_ws, size_t ws_size,
                              hipStream_t stream)
{
    const float* img = (const float*)d_in[0];
    const float* fs  = (const float*)d_in[2];
    const float* fr  = (const float*)d_in[3];
    float* out = (float*)d_out;

    int nImgTotal = in_sizes[0] / (HDIM * WDIM);   // 12
    size_t perImgBytes = (size_t)CELLS * 2 * sizeof(float);

    int maxChunk = (int)(ws_size / (2 * perImgBytes));
    if (maxChunk < 1) return;
    if (maxChunk > nImgTotal) maxChunk = nImgTotal;

    for (int base = 0; base < nImgTotal; base += maxChunk) {
        int c = nImgTotal - base;
        if (c > maxChunk) c = maxChunk;

        float* A = (float*)d_ws;
        float* B = A + (size_t)c * CELLS * 2;

        int nCells = c * GH * GW;
        int cellBlocks = (nCells + 63) / 64;
        splat_gather_kernel<<<cellBlocks, 256, 0, stream>>>(img, A, c, base);

        dim3 bgrid(GH, c);                         // 129 x c row blocks
        blur_yxz_row<<<bgrid, 256, 0, stream>>>((const float2*)A, (float2*)B, fs, fr);

        dim3 sgrid(HDIM / 8, c);
        slice_rows_kernel<<<sgrid, 256, 0, stream>>>(img, (const float2*)B, out, base);
    }
}

// Round 21
// 89.360 us; speedup vs baseline: 1.3463x; 1.0330x over previous
//
#include <hip/hip_runtime.h>

#define S_SIGMA 8
#define NBINS   16
#define HDIM    1024
#define WDIM    1024
#define GH      129   // (1024-1)/8 + 2
#define GW      129
#define GZ      17    // NBINS + 1
#define CELLS   (GH*GW*GZ)   // 282897 cells per image
#define ROWSZ   (GW*GZ)      // 2193 float2 per grid row
#define EPSV    1e-8f
#define FIXS    1048576.0f   // 2^20 fixed-point scale
#define FIXI    (1.0f/1048576.0f)

// Bijective XCD swizzle (m204): HW round-robins consecutive blockIdx across
// 8 XCDs; this remap gives each XCD a CONTIGUOUS work chunk so neighboring
// work items (which share input rows) hit the same XCD's L2.
__device__ __forceinline__ int xcd_swizzle(int orig, int nwg) {
    int q = nwg >> 3, r = nwg & 7;
    int xcd = orig & 7, off = orig >> 3;
    return (xcd < r ? xcd * (q + 1) : r * (q + 1) + (xcd - r) * q) + off;
}

// Grid A: [b][gy][gx][z].  Grid B (blurred): [b][gy][z][gx].

// ---- gather splat (r12, proven): 4 threads/cell, ds_add_u32 ----
__global__ __launch_bounds__(256) void splat_gather_kernel(
    const float* __restrict__ img, float* __restrict__ grid, int nImg, int imgBase,
    int nBlocks)
{
    __shared__ unsigned lval[16 * 64];   // [gz][cell], bank = cell%32
    __shared__ unsigned lwt [16 * 64];

    int tid = threadIdx.x;
    int c   = tid & 63;
    int q   = tid >> 6;
    int blk = xcd_swizzle(blockIdx.x, nBlocks);
    int cellIdx = blk * 64 + c;
    int total = nImg * GH * GW;

    for (int i = tid; i < 16 * 64; i += 256) { lval[i] = 0u; lwt[i] = 0u; }
    __syncthreads();

    if (cellIdx < total) {
        int b   = cellIdx / (GH * GW);
        int rem = cellIdx - b * (GH * GW);
        int gy  = rem / GW;
        int gx  = rem - gy * GW;
        const float* ib = img + (size_t)(imgBase + b) * (HDIM * WDIM);

        bool interior = (gx >= 1) & (gx <= 127) & (gy >= 1) & (gy <= 127);
        if (interior) {
            int py = gy & 1, px = gx & 1;
            int ylo = 8 * gy - 4 + py;
            int nr  = 9 - 2 * py;
            int ax  = 8 * gx - 4;
            for (int r = q; r < nr; r += 4) {
                const float* rp = ib + (size_t)(ylo + r) * WDIM + ax;
                float4 A = *(const float4*)rp;
                float4 B = *(const float4*)(rp + 4);
                float  cv = rp[8];
                float e7[7] = {A.y, A.z, A.w, B.x, B.y, B.z, B.w};
                #pragma unroll
                for (int j = 0; j < 7; ++j) {
                    float v = e7[j];
                    int gz = min(max((int)rintf(v * 15.0f), 0), 15);
                    atomicAdd(&lval[gz * 64 + c], (unsigned)rintf(v * FIXS));
                    atomicAdd(&lwt [gz * 64 + c], 1u);
                }
                if (!px) {
                    int gz = min(max((int)rintf(A.x * 15.0f), 0), 15);
                    atomicAdd(&lval[gz * 64 + c], (unsigned)rintf(A.x * FIXS));
                    atomicAdd(&lwt [gz * 64 + c], 1u);
                    gz = min(max((int)rintf(cv * 15.0f), 0), 15);
                    atomicAdd(&lval[gz * 64 + c], (unsigned)rintf(cv * FIXS));
                    atomicAdd(&lwt [gz * 64 + c], 1u);
                }
            }
        } else {
            int ylo = max(0, 8 * gy - 4 + (gy & 1));
            int yhi = min(HDIM - 1, 8 * gy + 4 - (gy & 1));
            int xlo = max(0, 8 * gx - 4 + (gx & 1));
            int xhi = min(WDIM - 1, 8 * gx + 4 - (gx & 1));
            for (int y = ylo + q; y <= yhi; y += 4) {
                const float* row = ib + (size_t)y * WDIM;
                for (int x = xlo; x <= xhi; ++x) {
                    float v = row[x];
                    int gz = min(max((int)rintf(v * 15.0f), 0), 15);
                    atomicAdd(&lval[gz * 64 + c], (unsigned)rintf(v * FIXS));
                    atomicAdd(&lwt [gz * 64 + c], 1u);
                }
            }
        }
    }
    __syncthreads();

    if (cellIdx < total) {
        float2* dst = (float2*)grid + (size_t)cellIdx * GZ;
        int zlo = q * 4;
        int zhi = (q == 3) ? 17 : zlo + 4;
        for (int z = zlo; z < zhi; ++z) {
            float2 o;
            if (z == 16) { o.x = 0.f; o.y = 0.f; }
            else {
                o.x = (float)lval[z * 64 + c] * FIXI;
                o.y = (float)lwt [z * 64 + c];
            }
            dst[z] = o;
        }
    }
}

// ---- single-pass blur (r20) + XCD swizzle on gy ----
// Block gy reads rows gy-2..gy+2; swizzle makes the 5-row window L2-local.
#define NRI 9   // ceil(2193/256)

__global__ __launch_bounds__(256) void blur_yxz_row(
    const float2* __restrict__ in, float2* __restrict__ out,
    const float* __restrict__ kfs, const float* __restrict__ kfr)
{
    __shared__ float2 sbin[ROWSZ];   // 17544 B

    int tid = threadIdx.x;
    int gy  = xcd_swizzle(blockIdx.x, GH);
    int b   = blockIdx.y;

    float ks[5] = {kfs[0], kfs[1], kfs[2], kfs[3], kfs[4]};
    float kr[5] = {kfr[0], kfr[1], kfr[2], kfr[3], kfr[4]};

    const float2* gb = in + (size_t)b * CELLS;
    int ylo = max(0, gy - 2), yhi = min(GH - 1, gy + 2);
    for (int i = tid; i < ROWSZ; i += 256) {
        float2 a; a.x = 0.f; a.y = 0.f;
        for (int yy = ylo; yy <= yhi; ++yy) {
            float k = ks[yy - gy + 2];
            float2 g = gb[(size_t)yy * ROWSZ + i];
            a.x += k * g.x;
            a.y += k * g.y;
        }
        sbin[i] = a;
    }
    __syncthreads();

    float2 rt[NRI];
    #pragma unroll
    for (int it = 0; it < NRI; ++it) {
        int o = tid + it * 256;
        float2 a; a.x = 0.f; a.y = 0.f;
        if (o < ROWSZ) {
            int gx = o / GZ;
            #pragma unroll
            for (int t = 0; t < 5; ++t) {
                int xx = gx + t - 2;
                if (xx >= 0 && xx < GW) {
                    float2 g = sbin[o + (t - 2) * GZ];
                    a.x += ks[t] * g.x;
                    a.y += ks[t] * g.y;
                }
            }
        }
        rt[it] = a;
    }
    __syncthreads();
    #pragma unroll
    for (int it = 0; it < NRI; ++it) {
        int o = tid + it * 256;
        if (o < ROWSZ) sbin[o] = rt[it];   // sbin = yx-blurred [gx][z]
    }
    __syncthreads();

    float2* ob = out + (size_t)b * CELLS + (size_t)gy * ROWSZ;
    for (int o2 = tid; o2 < ROWSZ; o2 += 256) {
        int z  = o2 / GW;
        int gx = o2 - z * GW;
        float2 a; a.x = 0.f; a.y = 0.f;
        #pragma unroll
        for (int t = 0; t < 5; ++t) {
            int zz = z + t - 2;
            if (zz >= 0 && zz < GZ) {
                float2 g = sbin[gx * GZ + zz];
                a.x += kr[t] * g.x;
                a.y += kr[t] * g.y;
            }
        }
        ob[o2] = a;
    }
}

// ---- slice (r12) + XCD swizzle on k (rows k,k+1 shared with neighbor) ----
#define XP2   136
#define RST   XP2
#define ZST   (2*XP2)

__global__ __launch_bounds__(256) void slice_rows_kernel(
    const float* __restrict__ img, const float2* __restrict__ grid,
    float* __restrict__ out, int imgBase)
{
    __shared__ float2 sg[GZ * ZST];   // 36992 B

    int tid = threadIdx.x;
    int k   = xcd_swizzle(blockIdx.x, HDIM / 8);
    int b   = blockIdx.y;

    const float2* gsrc = grid + (size_t)b * CELLS + (size_t)k * ROWSZ;
    for (int i = tid; i < 2 * ROWSZ; i += 256) {
        int r   = i / ROWSZ;
        int rem = i - r * ROWSZ;
        int z   = rem / GW;
        int x0  = rem - z * GW;
        sg[z * ZST + r * RST + x0] = gsrc[i];
    }
    __syncthreads();

    int x   = tid << 2;
    int x0v = tid >> 1;
    float txb = (float)(x & 7) * 0.125f;

    size_t rowBase = (size_t)(imgBase + b) * (HDIM * WDIM) + (size_t)(k << 3) * WDIM + x;

    #pragma unroll
    for (int r = 0; r < 8; ++r) {
        size_t pixBase = rowBase + (size_t)r * WDIM;
        float4 v4 = *(const float4*)(img + pixBase);
        float ty = (float)r * 0.125f;
        float wy0 = 1.f - ty, wy1 = ty;

        float vv[4] = {v4.x, v4.y, v4.z, v4.w};
        float rr[4];
        #pragma unroll
        for (int j = 0; j < 4; ++j) {
            float v  = vv[j];
            float fz = fminf(fmaxf(v * 15.0f, 0.0f), 15.0f);
            float zf = floorf(fz);
            int   z0 = (int)zf;
            float tz = fz - zf;
            float tx = txb + (float)j * 0.125f;
            float wx0 = 1.f - tx, wx1 = tx;
            float wz0 = 1.f - tz, wz1 = tz;

            int base = z0 * ZST + x0v;
            float2 g000 = sg[base];
            float2 g010 = sg[base + 1];
            float2 g100 = sg[base + RST];
            float2 g110 = sg[base + RST + 1];
            float2 g001 = sg[base + ZST];
            float2 g011 = sg[base + ZST + 1];
            float2 g101 = sg[base + ZST + RST];
            float2 g111 = sg[base + ZST + RST + 1];

            float ov = 0.f, ow = 0.f, w;
            w = wy0 * wx0 * wz0; ov += w * g000.x; ow += w * g000.y;
            w = wy0 * wx0 * wz1; ov += w * g001.x; ow += w * g001.y;
            w = wy0 * wx1 * wz0; ov += w * g010.x; ow += w * g010.y;
            w = wy0 * wx1 * wz1; ov += w * g011.x; ow += w * g011.y;
            w = wy1 * wx0 * wz0; ov += w * g100.x; ow += w * g100.y;
            w = wy1 * wx0 * wz1; ov += w * g101.x; ow += w * g101.y;
            w = wy1 * wx1 * wz0; ov += w * g110.x; ow += w * g110.y;
            w = wy1 * wx1 * wz1; ov += w * g111.x; ow += w * g111.y;
            rr[j] = ov / (ow + EPSV);
        }
        float4 r4; r4.x = rr[0]; r4.y = rr[1]; r4.z = rr[2]; r4.w = rr[3];
        *(float4*)(out + pixBase) = r4;
    }
}

extern "C" void kernel_launch(void* const* d_in, const int* in_sizes, int n_in,
                              void* d_out, int out_size, void* d_ws, size_t ws_size,
                              hipStream_t stream)
{
    const float* img = (const float*)d_in[0];
    const float* fs  = (const float*)d_in[2];
    const float* fr  = (const float*)d_in[3];
    float* out = (float*)d_out;

    int nImgTotal = in_sizes[0] / (HDIM * WDIM);   // 12
    size_t perImgBytes = (size_t)CELLS * 2 * sizeof(float);

    int maxChunk = (int)(ws_size / (2 * perImgBytes));
    if (maxChunk < 1) return;
    if (maxChunk > nImgTotal) maxChunk = nImgTotal;

    for (int base = 0; base < nImgTotal; base += maxChunk) {
        int c = nImgTotal - base;
        if (c > maxChunk) c = maxChunk;

        float* A = (float*)d_ws;
        float* B = A + (size_t)c * CELLS * 2;

        int nCells = c * GH * GW;
        int cellBlocks = (nCells + 63) / 64;
        splat_gather_kernel<<<cellBlocks, 256, 0, stream>>>(img, A, c, base, cellBlocks);

        dim3 bgrid(GH, c);
        blur_yxz_row<<<bgrid, 256, 0, stream>>>((const float2*)A, (float2*)B, fs, fr);

        dim3 sgrid(HDIM / 8, c);
        slice_rows_kernel<<<sgrid, 256, 0, stream>>>(img, (const float2*)B, out, base);
    }
}

// Round 22
// 89.214 us; speedup vs baseline: 1.3485x; 1.0016x over previous
//
#include <hip/hip_runtime.h>

#define S_SIGMA 8
#define NBINS   16
#define HDIM    1024
#define WDIM    1024
#define GH      129   // (1024-1)/8 + 2
#define GW      129
#define GZ      17    // NBINS + 1
#define CELLS   (GH*GW*GZ)   // 282897 cells per image
#define ROWSZ   (GW*GZ)      // 2193 float2 per grid row
#define EPSV    1e-8f
// packed bin: count in bits 25..31 (max 81 < 128), val*4096 in bits 0..24
// (max 81*4095 = 331K << 2^25, no carry into count field)
#define PKONE   (1u << 25)
#define PKMASK  0x1FFFFFFu
#define PKSCL   4096.0f
#define PKINV   (1.0f/4096.0f)

// Bijective XCD swizzle (m204): contiguous work chunk per XCD -> neighbor
// work items (sharing input rows) hit the same XCD's L2.
__device__ __forceinline__ int xcd_swizzle(int orig, int nwg) {
    int q = nwg >> 3, r = nwg & 7;
    int xcd = orig & 7, off = orig >> 3;
    return (xcd < r ? xcd * (q + 1) : r * (q + 1) + (xcd - r) * q) + off;
}

// Grid A: [b][gy][gx][z].  Grid B (blurred): [b][gy][z][gx].

// ---- gather splat: 4 threads/cell, ONE packed ds_add_u32 per pixel ----
__global__ __launch_bounds__(256) void splat_gather_kernel(
    const float* __restrict__ img, float* __restrict__ grid, int nImg, int imgBase,
    int nBlocks)
{
    __shared__ unsigned lbin[16 * 64];   // [gz][cell], bank = cell%32

    int tid = threadIdx.x;
    int c   = tid & 63;
    int q   = tid >> 6;
    int blk = xcd_swizzle(blockIdx.x, nBlocks);
    int cellIdx = blk * 64 + c;
    int total = nImg * GH * GW;

    for (int i = tid; i < 16 * 64; i += 256) lbin[i] = 0u;
    __syncthreads();

    if (cellIdx < total) {
        int b   = cellIdx / (GH * GW);
        int rem = cellIdx - b * (GH * GW);
        int gy  = rem / GW;
        int gx  = rem - gy * GW;
        const float* ib = img + (size_t)(imgBase + b) * (HDIM * WDIM);

        bool interior = (gx >= 1) & (gx <= 127) & (gy >= 1) & (gy <= 127);
        if (interior) {
            int py = gy & 1, px = gx & 1;
            int ylo = 8 * gy - 4 + py;
            int nr  = 9 - 2 * py;
            int ax  = 8 * gx - 4;
            for (int r = q; r < nr; r += 4) {
                const float* rp = ib + (size_t)(ylo + r) * WDIM + ax;
                float4 A = *(const float4*)rp;
                float4 B = *(const float4*)(rp + 4);
                float  cv = rp[8];
                float e7[7] = {A.y, A.z, A.w, B.x, B.y, B.z, B.w};
                #pragma unroll
                for (int j = 0; j < 7; ++j) {
                    float v = e7[j];
                    int gz = min(max((int)rintf(v * 15.0f), 0), 15);
                    atomicAdd(&lbin[gz * 64 + c], PKONE + (unsigned)rintf(v * PKSCL));
                }
                if (!px) {
                    int gz = min(max((int)rintf(A.x * 15.0f), 0), 15);
                    atomicAdd(&lbin[gz * 64 + c], PKONE + (unsigned)rintf(A.x * PKSCL));
                    gz = min(max((int)rintf(cv * 15.0f), 0), 15);
                    atomicAdd(&lbin[gz * 64 + c], PKONE + (unsigned)rintf(cv * PKSCL));
                }
            }
        } else {
            int ylo = max(0, 8 * gy - 4 + (gy & 1));
            int yhi = min(HDIM - 1, 8 * gy + 4 - (gy & 1));
            int xlo = max(0, 8 * gx - 4 + (gx & 1));
            int xhi = min(WDIM - 1, 8 * gx + 4 - (gx & 1));
            for (int y = ylo + q; y <= yhi; y += 4) {
                const float* row = ib + (size_t)y * WDIM;
                for (int x = xlo; x <= xhi; ++x) {
                    float v = row[x];
                    int gz = min(max((int)rintf(v * 15.0f), 0), 15);
                    atomicAdd(&lbin[gz * 64 + c], PKONE + (unsigned)rintf(v * PKSCL));
                }
            }
        }
    }
    __syncthreads();

    if (cellIdx < total) {
        float2* dst = (float2*)grid + (size_t)cellIdx * GZ;
        int zlo = q * 4;
        int zhi = (q == 3) ? 17 : zlo + 4;
        for (int z = zlo; z < zhi; ++z) {
            float2 o;
            if (z == 16) { o.x = 0.f; o.y = 0.f; }
            else {
                unsigned w = lbin[z * 64 + c];
                o.x = (float)(w & PKMASK) * PKINV;
                o.y = (float)(w >> 25);
            }
            dst[z] = o;
        }
    }
}

// ---- single-pass blur (r20) + XCD swizzle on gy ----
#define NRI 9   // ceil(2193/256)

__global__ __launch_bounds__(256) void blur_yxz_row(
    const float2* __restrict__ in, float2* __restrict__ out,
    const float* __restrict__ kfs, const float* __restrict__ kfr)
{
    __shared__ float2 sbin[ROWSZ];   // 17544 B

    int tid = threadIdx.x;
    int gy  = xcd_swizzle(blockIdx.x, GH);
    int b   = blockIdx.y;

    float ks[5] = {kfs[0], kfs[1], kfs[2], kfs[3], kfs[4]};
    float kr[5] = {kfr[0], kfr[1], kfr[2], kfr[3], kfr[4]};

    const float2* gb = in + (size_t)b * CELLS;
    int ylo = max(0, gy - 2), yhi = min(GH - 1, gy + 2);
    for (int i = tid; i < ROWSZ; i += 256) {
        float2 a; a.x = 0.f; a.y = 0.f;
        for (int yy = ylo; yy <= yhi; ++yy) {
            float k = ks[yy - gy + 2];
            float2 g = gb[(size_t)yy * ROWSZ + i];
            a.x += k * g.x;
            a.y += k * g.y;
        }
        sbin[i] = a;
    }
    __syncthreads();

    float2 rt[NRI];
    #pragma unroll
    for (int it = 0; it < NRI; ++it) {
        int o = tid + it * 256;
        float2 a; a.x = 0.f; a.y = 0.f;
        if (o < ROWSZ) {
            int gx = o / GZ;
            #pragma unroll
            for (int t = 0; t < 5; ++t) {
                int xx = gx + t - 2;
                if (xx >= 0 && xx < GW) {
                    float2 g = sbin[o + (t - 2) * GZ];
                    a.x += ks[t] * g.x;
                    a.y += ks[t] * g.y;
                }
            }
        }
        rt[it] = a;
    }
    __syncthreads();
    #pragma unroll
    for (int it = 0; it < NRI; ++it) {
        int o = tid + it * 256;
        if (o < ROWSZ) sbin[o] = rt[it];   // sbin = yx-blurred [gx][z]
    }
    __syncthreads();

    float2* ob = out + (size_t)b * CELLS + (size_t)gy * ROWSZ;
    for (int o2 = tid; o2 < ROWSZ; o2 += 256) {
        int z  = o2 / GW;
        int gx = o2 - z * GW;
        float2 a; a.x = 0.f; a.y = 0.f;
        #pragma unroll
        for (int t = 0; t < 5; ++t) {
            int zz = z + t - 2;
            if (zz >= 0 && zz < GZ) {
                float2 g = sbin[gx * GZ + zz];
                a.x += kr[t] * g.x;
                a.y += kr[t] * g.y;
            }
        }
        ob[o2] = a;
    }
}

// ---- slice (r12) + XCD swizzle on k ----
#define XP2   136
#define RST   XP2
#define ZST   (2*XP2)

__global__ __launch_bounds__(256) void slice_rows_kernel(
    const float* __restrict__ img, const float2* __restrict__ grid,
    float* __restrict__ out, int imgBase)
{
    __shared__ float2 sg[GZ * ZST];   // 36992 B

    int tid = threadIdx.x;
    int k   = xcd_swizzle(blockIdx.x, HDIM / 8);
    int b   = blockIdx.y;

    const float2* gsrc = grid + (size_t)b * CELLS + (size_t)k * ROWSZ;
    for (int i = tid; i < 2 * ROWSZ; i += 256) {
        int r   = i / ROWSZ;
        int rem = i - r * ROWSZ;
        int z   = rem / GW;
        int x0  = rem - z * GW;
        sg[z * ZST + r * RST + x0] = gsrc[i];
    }
    __syncthreads();

    int x   = tid << 2;
    int x0v = tid >> 1;
    float txb = (float)(x & 7) * 0.125f;

    size_t rowBase = (size_t)(imgBase + b) * (HDIM * WDIM) + (size_t)(k << 3) * WDIM + x;

    #pragma unroll
    for (int r = 0; r < 8; ++r) {
        size_t pixBase = rowBase + (size_t)r * WDIM;
        float4 v4 = *(const float4*)(img + pixBase);
        float ty = (float)r * 0.125f;
        float wy0 = 1.f - ty, wy1 = ty;

        float vv[4] = {v4.x, v4.y, v4.z, v4.w};
        float rr[4];
        #pragma unroll
        for (int j = 0; j < 4; ++j) {
            float v  = vv[j];
            float fz = fminf(fmaxf(v * 15.0f, 0.0f), 15.0f);
            float zf = floorf(fz);
            int   z0 = (int)zf;
            float tz = fz - zf;
            float tx = txb + (float)j * 0.125f;
            float wx0 = 1.f - tx, wx1 = tx;
            float wz0 = 1.f - tz, wz1 = tz;

            int base = z0 * ZST + x0v;
            float2 g000 = sg[base];
            float2 g010 = sg[base + 1];
            float2 g100 = sg[base + RST];
            float2 g110 = sg[base + RST + 1];
            float2 g001 = sg[base + ZST];
            float2 g011 = sg[base + ZST + 1];
            float2 g101 = sg[base + ZST + RST];
            float2 g111 = sg[base + ZST + RST + 1];

            float ov = 0.f, ow = 0.f, w;
            w = wy0 * wx0 * wz0; ov += w * g000.x; ow += w * g000.y;
            w = wy0 * wx0 * wz1; ov += w * g001.x; ow += w * g001.y;
            w = wy0 * wx1 * wz0; ov += w * g010.x; ow += w * g010.y;
            w = wy0 * wx1 * wz1; ov += w * g011.x; ow += w * g011.y;
            w = wy1 * wx0 * wz0; ov += w * g100.x; ow += w * g100.y;
            w = wy1 * wx0 * wz1; ov += w * g101.x; ow += w * g101.y;
            w = wy1 * wx1 * wz0; ov += w * g110.x; ow += w * g110.y;
            w = wy1 * wx1 * wz1; ov += w * g111.x; ow += w * g111.y;
            rr[j] = ov / (ow + EPSV);
        }
        float4 r4; r4.x = rr[0]; r4.y = rr[1]; r4.z = rr[2]; r4.w = rr[3];
        *(float4*)(out + pixBase) = r4;
    }
}

extern "C" void kernel_launch(void* const* d_in, const int* in_sizes, int n_in,
                              void* d_out, int out_size, void* d_ws, size_t ws_size,
                              hipStream_t stream)
{
    const float* img = (const float*)d_in[0];
    const float* fs  = (const float*)d_in[2];
    const float* fr  = (const float*)d_in[3];
    float* out = (float*)d_out;

    int nImgTotal = in_sizes[0] / (HDIM * WDIM);   // 12
    size_t perImgBytes = (size_t)CELLS * 2 * sizeof(float);

    int maxChunk = (int)(ws_size / (2 * perImgBytes));
    if (maxChunk < 1) return;
    if (maxChunk > nImgTotal) maxChunk = nImgTotal;

    for (int base = 0; base < nImgTotal; base += maxChunk) {
        int c = nImgTotal - base;
        if (c > maxChunk) c = maxChunk;

        float* A = (float*)d_ws;
        float* B = A + (size_t)c * CELLS * 2;

        int nCells = c * GH * GW;
        int cellBlocks = (nCells + 63) / 64;
        splat_gather_kernel<<<cellBlocks, 256, 0, stream>>>(img, A, c, base, cellBlocks);

        dim3 bgrid(GH, c);
        blur_yxz_row<<<bgrid, 256, 0, stream>>>((const float2*)A, (float2*)B, fs, fr);

        dim3 sgrid(HDIM / 8, c);
        slice_rows_kernel<<<sgrid, 256, 0, stream>>>(img, (const float2*)B, out, base);
    }
}